// Round 1
// baseline (124.016 us; speedup 1.0000x reference)
//
#include <hip/hip_runtime.h>

// Problem constants (match reference)
constexpr int P      = 8;
constexpr int B      = 160;
constexpr int T      = 32;
constexpr int MD     = 8;
constexpr int MA     = 8;
constexpr int ND     = 6;
constexpr int NA     = 6;
constexpr int NBT    = 20;
constexpr int K      = 11;
constexpr int MIN_SEP = 4;
constexpr int NPAIR  = ND * NA;   // 36
constexpr int TOTAL  = P * B * B; // 204800 (divisible by 256)

__global__ __launch_bounds__(256) void hbond_kernel(
    const float* __restrict__ coords,        // (P, B*T, 3)
    const float* __restrict__ pair_params,   // (ND, NA, 3): dmin, dmax, w
    const float* __restrict__ pair_poly,     // (ND, NA, K)
    const float* __restrict__ global_params, // (1, 3)
    const int*   __restrict__ block_type,    // (P, B)
    const int*   __restrict__ min_bond_sep,  // (P, B, B)
    const int*   __restrict__ n_donH,        // (NBT,)
    const int*   __restrict__ donH_inds,     // (NBT, MD)
    const int*   __restrict__ donH_type,     // (NBT, MD)
    const int*   __restrict__ n_acc,         // (NBT,)
    const int*   __restrict__ acc_inds,      // (NBT, MA)
    const int*   __restrict__ acc_type,      // (NBT, MA)
    float*       __restrict__ out)           // (P,)
{
    __shared__ float2 s_mm[NPAIR];      // (dmin^2, dmax^2)
    __shared__ float  s_w[NPAIR];
    __shared__ float  s_poly[NPAIR][K];

    if (threadIdx.x < NPAIR) {
        const int i = threadIdx.x;
        const float dmin = pair_params[i * 3 + 0];
        const float dmax = pair_params[i * 3 + 1];
        s_mm[i] = make_float2(dmin * dmin, dmax * dmax);
        s_w[i]  = pair_params[i * 3 + 2];
    }
    for (int i = threadIdx.x; i < NPAIR * K; i += 256)
        s_poly[i / K][i % K] = pair_poly[i];
    __syncthreads();

    const float g = global_params[0];

    const int idx = blockIdx.x * 256 + threadIdx.x;   // exactly TOTAL threads
    const int p   = idx / (B * B);                     // wave-uniform
    const int r   = idx - p * (B * B);
    const int b1  = r / B;                             // wave-(nearly-)uniform
    const int b2  = r - b1 * B;

    float acc = 0.f;

    const int  sep    = min_bond_sep[idx];             // layout (P,B,B) == idx
    const bool active = (b1 != b2) && (sep >= MIN_SEP);

    if (active) {
        const int bt1 = block_type[p * B + b1];
        const int bt2 = block_type[p * B + b2];
        const int nH  = n_donH[bt1];
        const int nAc = n_acc[bt2];
        const float* cbase = coords + (size_t)p * (B * T * 3);

        // Preload acceptor data (static indexing -> stays in VGPRs)
        float Ax[MA], Ay[MA], Az[MA];
        int   At[MA];
        #pragma unroll
        for (int a = 0; a < MA; ++a) {
            const int ai   = acc_inds[bt2 * MA + a];   // always a valid token index
            const float* c = cbase + (b2 * T + ai) * 3;
            Ax[a] = c[0]; Ay[a] = c[1]; Az[a] = c[2];
            At[a] = acc_type[bt2 * MA + a];
        }

        for (int h = 0; h < nH; ++h) {                 // nH wave-coherent (b1 uniform)
            const int hi = donH_inds[bt1 * MD + h];
            const int dt = donH_type[bt1 * MD + h];
            const float* c = cbase + (b1 * T + hi) * 3;
            const float Hx = c[0], Hy = c[1], Hz = c[2];
            const int drow = dt * NA;

            #pragma unroll
            for (int a = 0; a < MA; ++a) {
                if (a < nAc) {
                    const float dx = Hx - Ax[a];
                    const float dy = Hy - Ay[a];
                    const float dz = Hz - Az[a];
                    const float d2 = fmaf(dx, dx, fmaf(dy, dy, fmaf(dz, dz, 1e-12f)));
                    // conservative prefilter: dmin >= 1.0 -> dmin^2 >= 1.0;
                    // dmax <= 4.0 -> dmax^2 <= 16.0
                    if (d2 >= 0.95f && d2 <= 16.2f) {
                        const int pi = drow + At[a];
                        const float2 mm = s_mm[pi];
                        if (d2 >= mm.x && d2 <= mm.y) {
                            const float d = sqrtf(d2);
                            const float* cf = s_poly[pi];
                            float E = cf[0];
                            #pragma unroll
                            for (int k = 1; k < K; ++k)
                                E = fmaf(E, d, cf[k]);
                            acc = fmaf(s_w[pi], E, acc);
                        }
                    }
                }
            }
        }
        acc *= g;
    }

    // wave-64 reduction; p is uniform within each wave (B*B % 64 == 0)
    #pragma unroll
    for (int off = 32; off; off >>= 1)
        acc += __shfl_down(acc, off, 64);
    if ((threadIdx.x & 63) == 0)
        atomicAdd(&out[p], acc);
}

extern "C" void kernel_launch(void* const* d_in, const int* in_sizes, int n_in,
                              void* d_out, int out_size, void* d_ws, size_t ws_size,
                              hipStream_t stream) {
    const float* coords        = (const float*)d_in[0];
    const float* pair_params   = (const float*)d_in[1];
    const float* pair_poly     = (const float*)d_in[2];
    const float* global_params = (const float*)d_in[3];
    const int*   block_type    = (const int*)d_in[4];
    const int*   min_bond_sep  = (const int*)d_in[5];
    const int*   n_donH        = (const int*)d_in[6];
    const int*   donH_inds     = (const int*)d_in[7];
    const int*   donH_type     = (const int*)d_in[8];
    const int*   n_acc         = (const int*)d_in[9];
    const int*   acc_inds      = (const int*)d_in[10];
    const int*   acc_type      = (const int*)d_in[11];
    float* out = (float*)d_out;

    // harness poisons d_out with 0xAA before every timed launch
    hipMemsetAsync(out, 0, P * sizeof(float), stream);

    hbond_kernel<<<TOTAL / 256, 256, 0, stream>>>(
        coords, pair_params, pair_poly, global_params,
        block_type, min_bond_sep,
        n_donH, donH_inds, donH_type,
        n_acc, acc_inds, acc_type,
        out);
}